// Round 7
// baseline (856.919 us; speedup 1.0000x reference)
//
#include <hip/hip_runtime.h>
#include <math.h>

typedef __bf16 bf16x8 __attribute__((ext_vector_type(8)));
typedef float f32x4 __attribute__((ext_vector_type(4)));
typedef short short8v __attribute__((ext_vector_type(8)));

#define MARGIN 0.01f
#define NCAND 32

#define WAITL do { asm volatile("s_waitcnt lgkmcnt(0)" ::: "memory"); __builtin_amdgcn_sched_barrier(0); } while (0)
#define WAITV do { asm volatile("s_waitcnt vmcnt(0)" ::: "memory"); __builtin_amdgcn_sched_barrier(0); } while (0)
#define RBAR  do { __builtin_amdgcn_sched_barrier(0); __builtin_amdgcn_s_barrier(); } while (0)
#define BARR  __builtin_amdgcn_s_barrier()

#define MFMA_PHASE(NH, B0, B1) do { \
    WAITL; \
    __builtin_amdgcn_s_setprio(1); \
    _Pragma("unroll") \
    for (int mi = 0; mi < 8; ++mi) { \
      acc[mi][2*(NH)]   = __builtin_amdgcn_mfma_f32_16x16x32_bf16(a[mi], (B0), acc[mi][2*(NH)],   0, 0, 0); \
      acc[mi][2*(NH)+1] = __builtin_amdgcn_mfma_f32_16x16x32_bf16(a[mi], (B1), acc[mi][2*(NH)+1], 0, 0, 0); \
    } \
    __builtin_amdgcn_s_setprio(0); \
  } while (0)

// rule #17: keep loads alive without MFMA consumers
__device__ __forceinline__ void keep(const bf16x8& v) {
  f32x4 t = __builtin_bit_cast(f32x4, v);
  asm volatile("" :: "v"(t));
}
#define KEEP_PHASE(B0, B1) do { \
    WAITL; \
    _Pragma("unroll") \
    for (int mi = 0; mi < 8; ++mi) keep(a[mi]); \
    keep(B0); keep(B1); \
  } while (0)

__device__ __forceinline__ unsigned short f2bf(float f) {
  unsigned u = __float_as_uint(f);
  u += 0x7fffu + ((u >> 16) & 1u);
  return (unsigned short)(u >> 16);
}
__device__ __forceinline__ float tanh_fast(float x) {
  float e = __builtin_amdgcn_exp2f(x * 2.885390081777927f);
  return 1.f - 2.f * __builtin_amdgcn_rcpf(e + 1.f);
}
__device__ __forceinline__ void gl_lds16(const void* g, void* l) {
  __builtin_amdgcn_global_load_lds(
      (const __attribute__((address_space(1))) unsigned int*)g,
      (__attribute__((address_space(3))) unsigned int*)l, 16, 0, 0);
}

__global__ __launch_bounds__(256) void prep_inp_k(const float* __restrict__ x,
    const float* __restrict__ Wi, const float* __restrict__ bi, float* __restrict__ inp) {
  int gid = blockIdx.x * 256 + threadIdx.x;
  int b = gid >> 9, h = gid & 511;
  const float* xr = x + b * 512;
  const float* wr = Wi + h * 512;
  float acc = bi[h];
  #pragma unroll 4
  for (int k = 0; k < 512; k += 4) {
    float4 xv = *(const float4*)(xr + k);
    float4 wv = *(const float4*)(wr + k);
    acc += xv.x * wv.x + xv.y * wv.y + xv.z * wv.z + xv.w * wv.w;
  }
  inp[gid] = acc;
}

// Packed: region (strip, KT 0..7) = 256 rows x 64 k; slot s holds k-chunk s^(row&7).
__global__ __launch_bounds__(256) void prep_w_pack_k(const float* __restrict__ w0,
    const float* __restrict__ w1, const float* __restrict__ w2, const float* __restrict__ w3,
    short* __restrict__ Whi) {
  int gid = blockIdx.x * 256 + threadIdx.x;
  if (gid >= 131072) return;
  int s = gid & 7, r = (gid >> 3) & 255, KT = (gid >> 11) & 7, TN = gid >> 14;
  int n = TN * 256 + r;
  int g = n >> 9, h = n & 511;
  const float* w = (g == 0) ? w0 : (g == 1) ? w1 : (g == 2) ? w2 : w3;
  int k = KT * 64 + ((s ^ (r & 7)) * 8);
  float f[8];
  *(float4*)&f[0] = *(const float4*)(w + (size_t)h * 512 + k);
  *(float4*)&f[4] = *(const float4*)(w + (size_t)h * 512 + k + 4);
  short8v hv;
  #pragma unroll
  for (int i = 0; i < 8; ++i) hv[i] = (short)f2bf(f[i]);
  *(short8v*)(Whi + (size_t)gid * 8) = hv;
}

__global__ __launch_bounds__(256) void prep_ctx_pack_k(const float* __restrict__ ctx,
    short* __restrict__ Chi) {
  int gid = blockIdx.x * 256 + threadIdx.x;
  int s = gid & 7, r = (gid >> 3) & 255, KT = (gid >> 11) & 7, TM = gid >> 14;
  size_t m = (size_t)TM * 256 + r;
  int k = KT * 64 + ((s ^ (r & 7)) * 8);
  float f[8];
  *(float4*)&f[0] = *(const float4*)(ctx + m * 512 + k);
  *(float4*)&f[4] = *(const float4*)(ctx + m * 512 + k + 4);
  short8v hv;
  #pragma unroll
  for (int i = 0; i < 8; ++i) hv[i] = (short)f2bf(f[i]);
  *(short8v*)(Chi + (size_t)gid * 8) = hv;
}

// Ablation GEMM. V=0 full; V=1 no-staging; V=2 no-LDS-reads; V=3 no-MFMA;
// V=4 MFMA-only (no stage, no reads). V!=0 write scratch (garbage OK).
template<int V, bool PRESPLIT>
__global__ __launch_bounds__(512, 2) void gemm_abl_k(
    const float* __restrict__ ctx, const short* __restrict__ Chi,
    const short* __restrict__ Whi,
    const float* __restrict__ inp,
    const float* __restrict__ bc0, const float* __restrict__ bc1,
    const float* __restrict__ bc2, const float* __restrict__ bc3,
    const float* __restrict__ V_, float* __restrict__ att) {
  constexpr bool DO_STAGE = (V == 0 || V == 2 || V == 3);
  constexpr bool DO_READ  = (V == 0 || V == 1 || V == 3);
  constexpr bool DO_MFMA  = (V != 3);

  __shared__ __align__(16) short smem[2][2][16384];   // 128 KiB
  __shared__ float sV[256], sPre[256];

  const int t = threadIdx.x;
  int d = blockIdx.x + (blockIdx.y << 3);
  int work = (d & 7) * 256 + (d >> 3);
  int mt = work >> 3, nt = work & 7;
  int b = mt >> 3;
  int g = nt >> 1, h0 = (nt & 1) * 256;

  if (t < 256) {
    const float* bc = (g == 0) ? bc0 : (g == 1) ? bc1 : (g == 2) ? bc2 : bc3;
    sV[t] = V_[h0 + t];
    sPre[t] = inp[b * 512 + h0 + t] + bc[h0 + t];
  }

  const int toff = t * 8;
  auto stageA = [&](int tile) {
    const short* gA = Chi + ((size_t)(mt * 8 + tile)) * 16384 + toff;
    short* lA = &smem[tile & 1][0][0];
    gl_lds16(gA,         lA + toff);
    gl_lds16(gA + 4096,  lA + toff + 4096);
    gl_lds16(gA + 8192,  lA + toff + 8192);
    gl_lds16(gA + 12288, lA + toff + 12288);
  };
  auto stageB = [&](int tile) {
    const short* gB = Whi + ((size_t)(nt * 8 + tile)) * 16384 + toff;
    short* lB = &smem[tile & 1][1][0];
    gl_lds16(gB,         lB + toff);
    gl_lds16(gB + 4096,  lB + toff + 4096);
    gl_lds16(gB + 8192,  lB + toff + 8192);
    gl_lds16(gB + 12288, lB + toff + 12288);
  };
  auto stageA_reg = [&](int tile) {
    #pragma unroll
    for (int pass = 0; pass < 4; ++pass) {
      int cc = pass * 512 + t;
      int s = cc & 7, r = cc >> 3;
      int k = tile * 64 + ((s ^ (r & 7)) * 8);
      const float* src = ctx + ((size_t)mt * 256 + r) * 512 + k;
      float f[8];
      *(float4*)&f[0] = *(const float4*)src;
      *(float4*)&f[4] = *(const float4*)(src + 4);
      short8v hv;
      #pragma unroll
      for (int i = 0; i < 8; ++i) hv[i] = (short)f2bf(f[i]);
      *(short8v*)(&smem[tile & 1][0][r * 64 + s * 8]) = hv;
    }
  };

  f32x4 acc[8][4];
  #pragma unroll
  for (int i = 0; i < 8; ++i)
    #pragma unroll
    for (int j = 0; j < 4; ++j) acc[i][j] = (f32x4){0.f, 0.f, 0.f, 0.f};

  const int lane = t & 63, wid = t >> 6;
  const int wr = wid >> 2, wc = wid & 3;
  const int fr = lane & 15, fq = lane >> 4;
  const int slot = fq ^ (fr & 7);
  const int aoff = (wr * 128 + fr) * 64 + slot * 8;
  const int boff = (wc * 64 + fr) * 64 + slot * 8;

  if (PRESPLIT) stageA(0); else stageA_reg(0);
  stageB(0);
  WAITV;
  BARR;

  bf16x8 a[8];
  bf16x8 b0, b1;
  if constexpr (!DO_READ) {
    // fixed fragments from real tile-0 data, loaded once
    #pragma unroll
    for (int mi = 0; mi < 8; ++mi) a[mi] = *(const bf16x8*)(&smem[0][0][0] + aoff + mi * 1024);
    b0 = *(const bf16x8*)(&smem[0][1][0] + boff);
    b1 = *(const bf16x8*)(&smem[0][1][0] + boff + 1024);
    WAITL;
  }

  for (int tt = 0; tt < 8; ++tt) {
    short* sa = &smem[tt & 1][0][0];
    short* sb = &smem[tt & 1][1][0];
    const int ap1 = aoff ^ 32, bp1 = boff ^ 32;
    (void)sa; (void)sb;
    // P0
    if constexpr (DO_READ) {
      #pragma unroll
      for (int mi = 0; mi < 8; ++mi) a[mi] = *(const bf16x8*)(sa + aoff + mi * 1024);
      b0 = *(const bf16x8*)(sb + boff);
      b1 = *(const bf16x8*)(sb + boff + 1024);
    }
    if constexpr (DO_STAGE) { if (tt < 7) { if (PRESPLIT) stageA(tt + 1); else stageA_reg(tt + 1); } }
    RBAR;
    if constexpr (DO_MFMA) MFMA_PHASE(0, b0, b1); else KEEP_PHASE(b0, b1);
    BARR;
    // P1
    if constexpr (DO_READ) {
      b0 = *(const bf16x8*)(sb + boff + 2048);
      b1 = *(const bf16x8*)(sb + boff + 3072);
    }
    if constexpr (DO_STAGE) { if (tt < 7) stageB(tt + 1); }
    RBAR;
    if constexpr (DO_MFMA) MFMA_PHASE(1, b0, b1); else KEEP_PHASE(b0, b1);
    BARR;
    // P2
    if constexpr (DO_READ) {
      #pragma unroll
      for (int mi = 0; mi < 8; ++mi) a[mi] = *(const bf16x8*)(sa + ap1 + mi * 1024);
      b0 = *(const bf16x8*)(sb + bp1);
      b1 = *(const bf16x8*)(sb + bp1 + 1024);
    }
    RBAR;
    if constexpr (DO_MFMA) MFMA_PHASE(0, b0, b1); else KEEP_PHASE(b0, b1);
    BARR;
    // P3
    if constexpr (DO_READ) {
      b0 = *(const bf16x8*)(sb + bp1 + 2048);
      b1 = *(const bf16x8*)(sb + bp1 + 3072);
    }
    RBAR;
    if constexpr (DO_MFMA) MFMA_PHASE(1, b0, b1); else KEEP_PHASE(b0, b1);
    if constexpr (DO_STAGE) WAITV;
    BARR;
  }

  float vV[4], vP[4];
  #pragma unroll
  for (int ni = 0; ni < 4; ++ni) {
    int j = wc * 64 + ni * 16 + fr;
    vV[ni] = sV[j];
    vP[ni] = sPre[j];
  }
  size_t abase = (size_t)b * 8192 + (size_t)g * 2048;
  #pragma unroll
  for (int mi = 0; mi < 8; ++mi) {
    #pragma unroll
    for (int r = 0; r < 4; ++r) {
      float sum = 0.f;
      #pragma unroll
      for (int ni = 0; ni < 4; ++ni)
        sum += vV[ni] * tanh_fast(vP[ni] + acc[mi][ni][r]);
      sum += __shfl_xor(sum, 1, 64);
      sum += __shfl_xor(sum, 2, 64);
      sum += __shfl_xor(sum, 4, 64);
      sum += __shfl_xor(sum, 8, 64);
      if (fr == 0) {
        int s = (mt * 256 + wr * 128 + mi * 16 + fq * 4 + r) & 2047;
        atomicAdd(&att[abase + s], sum);
      }
    }
  }
}

__global__ __launch_bounds__(256) void tail_k(const float* __restrict__ att,
    const unsigned char* __restrict__ mask, const float* __restrict__ ctx,
    const float* __restrict__ Wc0, const float* __restrict__ Wc1,
    const float* __restrict__ Wc2, const float* __restrict__ Wc3,
    const float* __restrict__ bc0, const float* __restrict__ bc1,
    const float* __restrict__ bc2, const float* __restrict__ bc3,
    const float* __restrict__ inp, const float* __restrict__ V,
    float* __restrict__ out) {
  int b = blockIdx.x, t = threadIdx.x;
  __shared__ float sred[256];
  __shared__ float sctx[512];
  __shared__ int scnt;
  __shared__ int scand_j[NCAND];
  __shared__ float scand_a[NCAND];
  __shared__ float sexact[NCAND];

  if (t == 0) scnt = 0;
  float bm = -1e30f;
  for (int j = t; j < 8192; j += 256) {
    if (mask[b * 2048 + (j & 2047)]) continue;
    bm = fmaxf(bm, att[(size_t)b * 8192 + j]);
  }
  sred[t] = bm;
  __syncthreads();
  for (int s2 = 128; s2 > 0; s2 >>= 1) {
    if (t < s2) sred[t] = fmaxf(sred[t], sred[t + s2]);
    __syncthreads();
  }
  float mx = sred[0];
  float Lref = 10.f * tanhf(mx);
  __syncthreads();
  float se = 0.f;
  for (int j = t; j < 8192; j += 256) {
    if (mask[b * 2048 + (j & 2047)]) continue;
    float a = att[(size_t)b * 8192 + j];
    se += expf(10.f * tanhf(a) - Lref);
    if (a >= mx - MARGIN) {
      int slot = atomicAdd(&scnt, 1);
      if (slot < NCAND) { scand_j[slot] = j; scand_a[slot] = a; }
    }
  }
  sred[t] = se;
  __syncthreads();
  for (int s2 = 128; s2 > 0; s2 >>= 1) {
    if (t < s2) sred[t] += sred[t + s2];
    __syncthreads();
  }
  float den = sred[0];
  int n = min(scnt, NCAND);
  for (int j = t; j < 2048; j += 256)
    out[64 + b * 2048 + j] = mask[b * 2048 + j] ? 1.0f : 0.0f;
  for (int i = 0; i < n; ++i) {
    int jj = scand_j[i];
    int g = jj >> 11, s = jj & 2047;
    const float* W  = (g == 0) ? Wc0 : (g == 1) ? Wc1 : (g == 2) ? Wc2 : Wc3;
    const float* bc = (g == 0) ? bc0 : (g == 1) ? bc1 : (g == 2) ? bc2 : bc3;
    const float* cr = ctx + ((size_t)b * 2048 + s) * 512;
    __syncthreads();
    sctx[t] = cr[t];
    sctx[t + 256] = cr[t + 256];
    __syncthreads();
    float total = 0.f;
    #pragma unroll
    for (int hh = 0; hh < 2; ++hh) {
      int h = t + hh * 256;
      const float* wrp = W + (size_t)h * 512;
      float acc = 0.f;
      #pragma unroll 4
      for (int k = 0; k < 512; k += 4) {
        float4 wv = *(const float4*)(wrp + k);
        acc += wv.x * sctx[k] + wv.y * sctx[k + 1] + wv.z * sctx[k + 2] + wv.w * sctx[k + 3];
      }
      total += V[h] * tanhf(inp[b * 512 + h] + bc[h] + acc);
    }
    sred[t] = total;
    __syncthreads();
    for (int s2 = 128; s2 > 0; s2 >>= 1) {
      if (t < s2) sred[t] += sred[t + s2];
      __syncthreads();
    }
    if (t == 0) sexact[i] = sred[0];
  }
  __syncthreads();
  if (t == 0) {
    float dd = den, best = -1e30f;
    int bj = 0x7fffffff;
    for (int i = 0; i < n; ++i) {
      float e = sexact[i];
      int j = scand_j[i];
      dd += expf(10.f * tanhf(e) - Lref) - expf(10.f * tanhf(scand_a[i]) - Lref);
      if (e > best || (e == best && j < bj)) { best = e; bj = j; }
    }
    out[b] = (float)bj;
    out[32 + b] = expf(10.f * tanhf(best) - Lref) / dd;
  }
}

extern "C" void kernel_launch(void* const* d_in, const int* in_sizes, int n_in,
                              void* d_out, int out_size, void* d_ws, size_t ws_size,
                              hipStream_t stream) {
  const float* x    = (const float*)d_in[0];
  const float* ctx  = (const float*)d_in[1];
  const unsigned char* mask = (const unsigned char*)d_in[2];
  const float* Wi   = (const float*)d_in[3];
  const float* bi   = (const float*)d_in[4];
  const float* Wc0  = (const float*)d_in[5];
  const float* bc0  = (const float*)d_in[6];
  const float* Wc1  = (const float*)d_in[7];
  const float* bc1  = (const float*)d_in[8];
  const float* Wc2  = (const float*)d_in[9];
  const float* bc2  = (const float*)d_in[10];
  const float* Wc3  = (const float*)d_in[11];
  const float* bc3  = (const float*)d_in[12];
  const float* V    = (const float*)d_in[13];
  float* out = (float*)d_out;

  float* inp    = (float*)d_ws;            // 16384 f32
  float* att    = inp + 16384;             // 262144 f32
  short* Whi    = (short*)(att + 262144);  // 1048576 shorts
  short* Chi    = Whi + 1048576;           // 33554432 shorts
  float* attS   = (float*)(Chi + 33554432);// 262144 f32 scratch for ablation
  size_t need = (size_t)((char*)(attS + 262144) - (char*)d_ws);
  bool roomy = ws_size >= need;

  hipMemsetAsync(att, 0, 262144 * sizeof(float), stream);
  prep_inp_k<<<64, 256, 0, stream>>>(x, Wi, bi, inp);
  prep_w_pack_k<<<512, 256, 0, stream>>>(Wc0, Wc1, Wc2, Wc3, Whi);
  if (roomy) {
    prep_ctx_pack_k<<<16384, 256, 0, stream>>>(ctx, Chi);
    gemm_abl_k<0, true><<<dim3(8, 256), 512, 0, stream>>>(ctx, Chi, Whi,
        inp, bc0, bc1, bc2, bc3, V, att);
    // ablation probes (outputs unused; within-probe component timing)
    gemm_abl_k<1, true><<<dim3(8, 256), 512, 0, stream>>>(ctx, Chi, Whi,
        inp, bc0, bc1, bc2, bc3, V, attS);
    gemm_abl_k<2, true><<<dim3(8, 256), 512, 0, stream>>>(ctx, Chi, Whi,
        inp, bc0, bc1, bc2, bc3, V, attS);
    gemm_abl_k<3, true><<<dim3(8, 256), 512, 0, stream>>>(ctx, Chi, Whi,
        inp, bc0, bc1, bc2, bc3, V, attS);
    gemm_abl_k<4, true><<<dim3(8, 256), 512, 0, stream>>>(ctx, Chi, Whi,
        inp, bc0, bc1, bc2, bc3, V, attS);
  } else {
    gemm_abl_k<0, false><<<dim3(8, 256), 512, 0, stream>>>(ctx, nullptr, Whi,
        inp, bc0, bc1, bc2, bc3, V, att);
  }
  tail_k<<<32, 256, 0, stream>>>(att, mask, ctx, Wc0, Wc1, Wc2, Wc3,
      bc0, bc1, bc2, bc3, inp, V, out);
}

// Round 8
// 322.270 us; speedup vs baseline: 2.6590x; 2.6590x over previous
//
#include <hip/hip_runtime.h>
#include <math.h>

typedef __bf16 bf16x8 __attribute__((ext_vector_type(8)));
typedef float f32x4 __attribute__((ext_vector_type(4)));
typedef short short8v __attribute__((ext_vector_type(8)));

#define MARGIN 0.01f
#define NCAND 32

#define WAITL  do { asm volatile("s_waitcnt lgkmcnt(0)" ::: "memory"); __builtin_amdgcn_sched_barrier(0); } while (0)
#define WAITV0 do { asm volatile("s_waitcnt vmcnt(0)" ::: "memory"); __builtin_amdgcn_sched_barrier(0); } while (0)
#define WAITV4 do { asm volatile("s_waitcnt vmcnt(4)" ::: "memory"); __builtin_amdgcn_sched_barrier(0); } while (0)
#define WAITV8 do { asm volatile("s_waitcnt vmcnt(8)" ::: "memory"); __builtin_amdgcn_sched_barrier(0); } while (0)
#define RBAR   do { __builtin_amdgcn_sched_barrier(0); __builtin_amdgcn_s_barrier(); } while (0)
#define BARR   __builtin_amdgcn_s_barrier()

// 16 MFMA: 8 mi x 2 ni (NH selects ni-pair), K=32 (one instr per frag pair).
#define MFMA_PHASE(NH, B0, B1) do { \
    WAITL; \
    __builtin_amdgcn_s_setprio(1); \
    _Pragma("unroll") \
    for (int mi = 0; mi < 8; ++mi) { \
      acc[mi][2*(NH)]   = __builtin_amdgcn_mfma_f32_16x16x32_bf16(a[mi], (B0), acc[mi][2*(NH)],   0, 0, 0); \
      acc[mi][2*(NH)+1] = __builtin_amdgcn_mfma_f32_16x16x32_bf16(a[mi], (B1), acc[mi][2*(NH)+1], 0, 0, 0); \
    } \
    __builtin_amdgcn_s_setprio(0); \
  } while (0)

__device__ __forceinline__ unsigned short f2bf(float f) {
  unsigned u = __float_as_uint(f);
  u += 0x7fffu + ((u >> 16) & 1u);
  return (unsigned short)(u >> 16);
}
__device__ __forceinline__ float tanh_fast(float x) {
  float e = __builtin_amdgcn_exp2f(x * 2.885390081777927f);
  return 1.f - 2.f * __builtin_amdgcn_rcpf(e + 1.f);
}
__device__ __forceinline__ void gl_lds16(const void* g, void* l) {
  __builtin_amdgcn_global_load_lds(
      (const __attribute__((address_space(1))) unsigned int*)g,
      (__attribute__((address_space(3))) unsigned int*)l, 16, 0, 0);
}

__global__ __launch_bounds__(256) void prep_inp_k(const float* __restrict__ x,
    const float* __restrict__ Wi, const float* __restrict__ bi, float* __restrict__ inp) {
  int gid = blockIdx.x * 256 + threadIdx.x;
  int b = gid >> 9, h = gid & 511;
  const float* xr = x + b * 512;
  const float* wr = Wi + h * 512;
  float acc = bi[h];
  #pragma unroll 4
  for (int k = 0; k < 512; k += 4) {
    float4 xv = *(const float4*)(xr + k);
    float4 wv = *(const float4*)(wr + k);
    acc += xv.x * wv.x + xv.y * wv.y + xv.z * wv.z + xv.w * wv.w;
  }
  inp[gid] = acc;
}

// Packed (R5-proven layout): region (strip, KS 0..15) = 256 rows x 32 k.
// Slot c of a row holds DATA k-chunk c ^ ((row>>1)&3): conflict-free b128
// reads; global_load_lds stays linear (pre-swizzled source, rule #21).
__global__ __launch_bounds__(256) void prep_w_pack_k(const float* __restrict__ w0,
    const float* __restrict__ w1, const float* __restrict__ w2, const float* __restrict__ w3,
    short* __restrict__ Whi) {
  int gid = blockIdx.x * 256 + threadIdx.x;
  if (gid >= 131072) return;
  int c = gid & 3, row = (gid >> 2) & 255, TK = gid >> 10;  // TK = TN*16+KS
  int TN = TK >> 4, KS = TK & 15;
  int n = TN * 256 + row;
  int g = n >> 9, h = n & 511;
  const float* w = (g == 0) ? w0 : (g == 1) ? w1 : (g == 2) ? w2 : w3;
  int csrc = c ^ ((row >> 1) & 3);
  const float* src = w + (size_t)h * 512 + KS * 32 + csrc * 8;
  float f[8];
  *(float4*)&f[0] = *(const float4*)(src);
  *(float4*)&f[4] = *(const float4*)(src + 4);
  short8v hv;
  #pragma unroll
  for (int i = 0; i < 8; ++i) hv[i] = (short)f2bf(f[i]);
  *(short8v*)(Whi + (size_t)gid * 8) = hv;
}

__global__ __launch_bounds__(256) void prep_ctx_pack_k(const float* __restrict__ ctx,
    short* __restrict__ Chi) {
  int gid = blockIdx.x * 256 + threadIdx.x;
  int c = gid & 3, row = (gid >> 2) & 255, TK = gid >> 10;  // TK = TM*16+KS
  int TM = TK >> 4, KS = TK & 15;
  size_t m = (size_t)TM * 256 + row;
  int csrc = c ^ ((row >> 1) & 3);
  int k = KS * 32 + csrc * 8;
  float f[8];
  *(float4*)&f[0] = *(const float4*)(ctx + m * 512 + k);
  *(float4*)&f[4] = *(const float4*)(ctx + m * 512 + k + 4);
  short8v hv;
  #pragma unroll
  for (int i = 0; i < 8; ++i) hv[i] = (short)f2bf(f[i]);
  *(short8v*)(Chi + (size_t)gid * 8) = hv;
}

// Main: 256x256 tile, 16 K-tiles of BK=32, 8 waves (2x4), per-wave 128x64.
// 4-deep LDS ring (4 x 32KB), TRUE counted vmcnt (T4): stage tile t+3 during
// tile t, wait vmcnt(8) per tile boundary — loads never drain to 0 mid-loop.
template<bool PRESPLIT>
__global__ __launch_bounds__(512, 2) void gemm_att_k(
    const float* __restrict__ ctx, const short* __restrict__ Chi,
    const short* __restrict__ Whi,
    const float* __restrict__ inp,
    const float* __restrict__ bc0, const float* __restrict__ bc1,
    const float* __restrict__ bc2, const float* __restrict__ bc3,
    const float* __restrict__ V, float* __restrict__ att) {
  __shared__ __align__(16) short smem[4][2][8192];   // 128 KiB: [ring][A|B]
  __shared__ float sV[256], sPre[256];

  const int t = threadIdx.x;
  int d = blockIdx.x + (blockIdx.y << 3);
  int work = (d & 7) * 256 + (d >> 3);           // XCD-contiguous chunks
  int mt = work >> 3, nt = work & 7;
  int b = mt >> 3;
  int g = nt >> 1, h0 = (nt & 1) * 256;

  if (t < 256) {
    const float* bc = (g == 0) ? bc0 : (g == 1) ? bc1 : (g == 2) ? bc2 : bc3;
    sV[t] = V[h0 + t];
    sPre[t] = inp[b * 512 + h0 + t] + bc[h0 + t];
  }

  const int toff = t * 8;   // t*16 bytes; tile region = 8192 shorts = 2 loads
  auto stageA = [&](int tile) {
    const short* gA = Chi + (((size_t)mt * 16 + tile) << 13) + toff;
    short* lA = &smem[tile & 3][0][0];
    gl_lds16(gA,        lA + toff);
    gl_lds16(gA + 4096, lA + toff + 4096);
  };
  auto stageB = [&](int tile) {
    const short* gB = Whi + (((size_t)nt * 16 + tile) << 13) + toff;
    short* lB = &smem[tile & 3][1][0];
    gl_lds16(gB,        lB + toff);
    gl_lds16(gB + 4096, lB + toff + 4096);
  };
  auto stageA_reg = [&](int tile) {    // fallback: fp32 ctx -> bf16 ds_write
    #pragma unroll
    for (int pass = 0; pass < 2; ++pass) {
      int cc = pass * 512 + t;         // chunk 0..1023
      int c = cc & 3, r = cc >> 2;
      int csrc = c ^ ((r >> 1) & 3);
      int k = tile * 32 + csrc * 8;
      const float* src = ctx + ((size_t)mt * 256 + r) * 512 + k;
      float f[8];
      *(float4*)&f[0] = *(const float4*)src;
      *(float4*)&f[4] = *(const float4*)(src + 4);
      short8v hv;
      #pragma unroll
      for (int i = 0; i < 8; ++i) hv[i] = (short)f2bf(f[i]);
      *(short8v*)(&smem[tile & 3][0][r * 32 + c * 8]) = hv;
    }
  };

  f32x4 acc[8][4];
  #pragma unroll
  for (int i = 0; i < 8; ++i)
    #pragma unroll
    for (int j = 0; j < 4; ++j) acc[i][j] = (f32x4){0.f, 0.f, 0.f, 0.f};

  const int lane = t & 63, wid = t >> 6;
  const int wr = wid >> 2, wc = wid & 3;
  const int fr = lane & 15, fq = lane >> 4;
  const int csw = fq ^ ((fr >> 1) & 3);          // swizzled chunk (per-thread const)
  const int abase = (wr * 128 + fr) * 32 + csw * 8;
  const int bbase = (wc * 64 + fr) * 32 + csw * 8;

  // prologue: tiles 0,1,2 staged; wait tile0 (allow 8 outstanding = t1,t2)
  if constexpr (PRESPLIT) {
    stageA(0); stageB(0); stageA(1); stageB(1); stageA(2); stageB(2);
    WAITV8;
  } else {
    stageA_reg(0); stageB(0);
    WAITV0;
  }
  BARR;

  #pragma unroll
  for (int tt = 0; tt < 16; ++tt) {
    const short* sa = &smem[tt & 3][0][0];
    const short* sb = &smem[tt & 3][1][0];
    bf16x8 a[8], b0, b1;
    // P1: A frags (held for both phases) + B cols 0..127; stage A(t+3)
    #pragma unroll
    for (int mi = 0; mi < 8; ++mi)
      a[mi] = *(const bf16x8*)(sa + abase + mi * 512);
    b0 = *(const bf16x8*)(sb + bbase);
    b1 = *(const bf16x8*)(sb + bbase + 512);
    if constexpr (PRESPLIT) { if (tt < 13) stageA(tt + 3); }
    else                    { if (tt < 15) stageA_reg(tt + 1); }
    RBAR;
    MFMA_PHASE(0, b0, b1);
    BARR;
    // P2: B cols 128..255; stage B(t+3); counted wait at tile boundary
    b0 = *(const bf16x8*)(sb + bbase + 1024);
    b1 = *(const bf16x8*)(sb + bbase + 1536);
    if constexpr (PRESPLIT) { if (tt < 13) stageB(tt + 3); }
    else                    { if (tt < 15) stageB(tt + 1); }
    RBAR;
    MFMA_PHASE(1, b0, b1);
    if constexpr (PRESPLIT) {
      if (tt <= 12) { WAITV8; }          // t+1,t+2,t+3 stay in flight
      else if (tt == 13) { WAITV4; }     // drain 8 -> 4
      else if (tt == 14) { WAITV0; }     // -> 0; tt==15: nothing outstanding
    } else {
      if (tt < 15) { WAITV0; }
    }
    BARR;
  }

  // epilogue: att[b, g*2048 + s] += sum_n V[h]*tanh(pre[h] + Y[n,s])
  float vV[4], vP[4];
  #pragma unroll
  for (int ni = 0; ni < 4; ++ni) {
    int j = wc * 64 + ni * 16 + fr;
    vV[ni] = sV[j];
    vP[ni] = sPre[j];
  }
  size_t abatt = (size_t)b * 8192 + (size_t)g * 2048;
  #pragma unroll
  for (int mi = 0; mi < 8; ++mi) {
    #pragma unroll
    for (int r = 0; r < 4; ++r) {
      float sum = 0.f;
      #pragma unroll
      for (int ni = 0; ni < 4; ++ni)
        sum += vV[ni] * tanh_fast(vP[ni] + acc[mi][ni][r]);
      sum += __shfl_xor(sum, 1, 64);
      sum += __shfl_xor(sum, 2, 64);
      sum += __shfl_xor(sum, 4, 64);
      sum += __shfl_xor(sum, 8, 64);
      if (fr == 0) {
        int s = (mt * 256 + wr * 128 + mi * 16 + fq * 4 + r) & 2047;
        atomicAdd(&att[abatt + s], sum);
      }
    }
  }
}

// Fused tail: max + denom + candidates, exact fp32 rescore, final outputs.
__global__ __launch_bounds__(256) void tail_k(const float* __restrict__ att,
    const unsigned char* __restrict__ mask, const float* __restrict__ ctx,
    const float* __restrict__ Wc0, const float* __restrict__ Wc1,
    const float* __restrict__ Wc2, const float* __restrict__ Wc3,
    const float* __restrict__ bc0, const float* __restrict__ bc1,
    const float* __restrict__ bc2, const float* __restrict__ bc3,
    const float* __restrict__ inp, const float* __restrict__ V,
    float* __restrict__ out) {
  int b = blockIdx.x, t = threadIdx.x;
  __shared__ float sred[256];
  __shared__ float sctx[512];
  __shared__ int scnt;
  __shared__ int scand_j[NCAND];
  __shared__ float scand_a[NCAND];
  __shared__ float sexact[NCAND];

  if (t == 0) scnt = 0;
  float bm = -1e30f;
  for (int j = t; j < 8192; j += 256) {
    if (mask[b * 2048 + (j & 2047)]) continue;
    bm = fmaxf(bm, att[(size_t)b * 8192 + j]);
  }
  sred[t] = bm;
  __syncthreads();
  for (int s2 = 128; s2 > 0; s2 >>= 1) {
    if (t < s2) sred[t] = fmaxf(sred[t], sred[t + s2]);
    __syncthreads();
  }
  float mx = sred[0];
  float Lref = 10.f * tanhf(mx);
  __syncthreads();
  float se = 0.f;
  for (int j = t; j < 8192; j += 256) {
    if (mask[b * 2048 + (j & 2047)]) continue;
    float a = att[(size_t)b * 8192 + j];
    se += expf(10.f * tanhf(a) - Lref);
    if (a >= mx - MARGIN) {
      int slot = atomicAdd(&scnt, 1);
      if (slot < NCAND) { scand_j[slot] = j; scand_a[slot] = a; }
    }
  }
  sred[t] = se;
  __syncthreads();
  for (int s2 = 128; s2 > 0; s2 >>= 1) {
    if (t < s2) sred[t] += sred[t + s2];
    __syncthreads();
  }
  float den = sred[0];
  int n = min(scnt, NCAND);
  for (int j = t; j < 2048; j += 256)
    out[64 + b * 2048 + j] = mask[b * 2048 + j] ? 1.0f : 0.0f;
  for (int i = 0; i < n; ++i) {
    int jj = scand_j[i];
    int g = jj >> 11, s = jj & 2047;
    const float* W  = (g == 0) ? Wc0 : (g == 1) ? Wc1 : (g == 2) ? Wc2 : Wc3;
    const float* bc = (g == 0) ? bc0 : (g == 1) ? bc1 : (g == 2) ? bc2 : bc3;
    const float* cr = ctx + ((size_t)b * 2048 + s) * 512;
    __syncthreads();
    sctx[t] = cr[t];
    sctx[t + 256] = cr[t + 256];
    __syncthreads();
    float total = 0.f;
    #pragma unroll
    for (int hh = 0; hh < 2; ++hh) {
      int h = t + hh * 256;
      const float* wrp = W + (size_t)h * 512;
      float acc = 0.f;
      #pragma unroll 4
      for (int k = 0; k < 512; k += 4) {
        float4 wv = *(const float4*)(wrp + k);
        acc += wv.x * sctx[k] + wv.y * sctx[k + 1] + wv.z * sctx[k + 2] + wv.w * sctx[k + 3];
      }
      total += V[h] * tanhf(inp[b * 512 + h] + bc[h] + acc);
    }
    sred[t] = total;
    __syncthreads();
    for (int s2 = 128; s2 > 0; s2 >>= 1) {
      if (t < s2) sred[t] += sred[t + s2];
      __syncthreads();
    }
    if (t == 0) sexact[i] = sred[0];
  }
  __syncthreads();
  if (t == 0) {
    float dd = den, best = -1e30f;
    int bj = 0x7fffffff;
    for (int i = 0; i < n; ++i) {
      float e = sexact[i];
      int j = scand_j[i];
      dd += expf(10.f * tanhf(e) - Lref) - expf(10.f * tanhf(scand_a[i]) - Lref);
      if (e > best || (e == best && j < bj)) { best = e; bj = j; }
    }
    out[b] = (float)bj;
    out[32 + b] = expf(10.f * tanhf(best) - Lref) / dd;
  }
}

extern "C" void kernel_launch(void* const* d_in, const int* in_sizes, int n_in,
                              void* d_out, int out_size, void* d_ws, size_t ws_size,
                              hipStream_t stream) {
  const float* x    = (const float*)d_in[0];
  const float* ctx  = (const float*)d_in[1];
  const unsigned char* mask = (const unsigned char*)d_in[2];
  const float* Wi   = (const float*)d_in[3];
  const float* bi   = (const float*)d_in[4];
  const float* Wc0  = (const float*)d_in[5];
  const float* bc0  = (const float*)d_in[6];
  const float* Wc1  = (const float*)d_in[7];
  const float* bc1  = (const float*)d_in[8];
  const float* Wc2  = (const float*)d_in[9];
  const float* bc2  = (const float*)d_in[10];
  const float* Wc3  = (const float*)d_in[11];
  const float* bc3  = (const float*)d_in[12];
  const float* V    = (const float*)d_in[13];
  float* out = (float*)d_out;

  float* inp    = (float*)d_ws;            // 16384 f32
  float* att    = inp + 16384;             // 262144 f32
  short* Whi    = (short*)(att + 262144);  // 1048576 shorts
  short* Chi    = Whi + 1048576;           // 33554432 shorts
  size_t need = (size_t)((char*)(Chi + 33554432) - (char*)d_ws);
  bool presplit = ws_size >= need;

  hipMemsetAsync(att, 0, 262144 * sizeof(float), stream);
  prep_inp_k<<<64, 256, 0, stream>>>(x, Wi, bi, inp);
  prep_w_pack_k<<<512, 256, 0, stream>>>(Wc0, Wc1, Wc2, Wc3, Whi);
  if (presplit) {
    prep_ctx_pack_k<<<16384, 256, 0, stream>>>(ctx, Chi);
    gemm_att_k<true><<<dim3(8, 256), 512, 0, stream>>>(ctx, Chi, Whi,
        inp, bc0, bc1, bc2, bc3, V, att);
  } else {
    gemm_att_k<false><<<dim3(8, 256), 512, 0, stream>>>(ctx, nullptr, Whi,
        inp, bc0, bc1, bc2, bc3, V, att);
  }
  tail_k<<<32, 256, 0, stream>>>(att, mask, ctx, Wc0, Wc1, Wc2, Wc3,
      bc0, bc1, bc2, bc3, inp, V, out);
}

// Round 11
// 314.628 us; speedup vs baseline: 2.7236x; 1.0243x over previous
//
#include <hip/hip_runtime.h>
#include <math.h>

typedef __bf16 bf16x8 __attribute__((ext_vector_type(8)));
typedef float f32x4 __attribute__((ext_vector_type(4)));
typedef short short8v __attribute__((ext_vector_type(8)));

#define MARGIN 0.01f
#define NCAND 32

#define WAITL  do { asm volatile("s_waitcnt lgkmcnt(0)" ::: "memory"); __builtin_amdgcn_sched_barrier(0); } while (0)
#define WAITV0 do { asm volatile("s_waitcnt vmcnt(0)" ::: "memory"); __builtin_amdgcn_sched_barrier(0); } while (0)
#define WAITV4 do { asm volatile("s_waitcnt vmcnt(4)" ::: "memory"); __builtin_amdgcn_sched_barrier(0); } while (0)
#define WAITV8 do { asm volatile("s_waitcnt vmcnt(8)" ::: "memory"); __builtin_amdgcn_sched_barrier(0); } while (0)
#define BARR   do { __builtin_amdgcn_s_barrier(); __builtin_amdgcn_sched_barrier(0); } while (0)

__device__ __forceinline__ unsigned short f2bf(float f) {
  unsigned u = __float_as_uint(f);
  u += 0x7fffu + ((u >> 16) & 1u);
  return (unsigned short)(u >> 16);
}
__device__ __forceinline__ float tanh_fast(float x) {
  float e = __builtin_amdgcn_exp2f(x * 2.885390081777927f);
  return 1.f - 2.f * __builtin_amdgcn_rcpf(e + 1.f);
}
__device__ __forceinline__ void gl_lds16(const void* g, void* l) {
  __builtin_amdgcn_global_load_lds(
      (const __attribute__((address_space(1))) unsigned int*)g,
      (__attribute__((address_space(3))) unsigned int*)l, 16, 0, 0);
}
// Sum over each 16-lane row via DPP row_shr (VALU pipe). row_shr:n => lane i
// receives lane i-n (0 if out of row, bound_ctrl) -- sum lands in LANE 15.
__device__ __forceinline__ float dpp_row_reduce(float v) {
  int x;
  x = __builtin_amdgcn_update_dpp(0, __builtin_bit_cast(int, v), 0x118, 0xf, 0xf, true);
  v += __builtin_bit_cast(float, x);   // += lane-8
  x = __builtin_amdgcn_update_dpp(0, __builtin_bit_cast(int, v), 0x114, 0xf, 0xf, true);
  v += __builtin_bit_cast(float, x);   // += lane-4
  x = __builtin_amdgcn_update_dpp(0, __builtin_bit_cast(int, v), 0x112, 0xf, 0xf, true);
  v += __builtin_bit_cast(float, x);   // += lane-2
  x = __builtin_amdgcn_update_dpp(0, __builtin_bit_cast(int, v), 0x111, 0xf, 0xf, true);
  v += __builtin_bit_cast(float, x);   // += lane-1
  return v;                            // lane 15 holds the row sum
}

__global__ __launch_bounds__(256) void prep_inp_k(const float* __restrict__ x,
    const float* __restrict__ Wi, const float* __restrict__ bi, float* __restrict__ inp) {
  int gid = blockIdx.x * 256 + threadIdx.x;
  int b = gid >> 9, h = gid & 511;
  const float* xr = x + b * 512;
  const float* wr = Wi + h * 512;
  float acc = bi[h];
  #pragma unroll 4
  for (int k = 0; k < 512; k += 4) {
    float4 xv = *(const float4*)(xr + k);
    float4 wv = *(const float4*)(wr + k);
    acc += xv.x * wv.x + xv.y * wv.y + xv.z * wv.z + xv.w * wv.w;
  }
  inp[gid] = acc;
}

// Packed (NO swizzle): region (strip, KS 0..15) = 256 rows x 32 k, row-major.
__global__ __launch_bounds__(256) void prep_w_pack_k(const float* __restrict__ w0,
    const float* __restrict__ w1, const float* __restrict__ w2, const float* __restrict__ w3,
    short* __restrict__ Whi) {
  int gid = blockIdx.x * 256 + threadIdx.x;
  if (gid >= 131072) return;
  int c = gid & 3, row = (gid >> 2) & 255, TK = gid >> 10;  // TK = TN*16+KS
  int TN = TK >> 4, KS = TK & 15;
  int n = TN * 256 + row;
  int g = n >> 9, h = n & 511;
  const float* w = (g == 0) ? w0 : (g == 1) ? w1 : (g == 2) ? w2 : w3;
  const float* src = w + (size_t)h * 512 + KS * 32 + c * 8;
  float f[8];
  *(float4*)&f[0] = *(const float4*)(src);
  *(float4*)&f[4] = *(const float4*)(src + 4);
  short8v hv;
  #pragma unroll
  for (int i = 0; i < 8; ++i) hv[i] = (short)f2bf(f[i]);
  *(short8v*)(Whi + (size_t)gid * 8) = hv;
}

__global__ __launch_bounds__(256) void prep_ctx_pack_k(const float* __restrict__ ctx,
    short* __restrict__ Chi) {
  int gid = blockIdx.x * 256 + threadIdx.x;
  int c = gid & 3, row = (gid >> 2) & 255, TK = gid >> 10;  // TK = TM*16+KS
  int TM = TK >> 4, KS = TK & 15;
  size_t m = (size_t)TM * 256 + row;
  int k = KS * 32 + c * 8;
  float f[8];
  *(float4*)&f[0] = *(const float4*)(ctx + m * 512 + k);
  *(float4*)&f[4] = *(const float4*)(ctx + m * 512 + k + 4);
  short8v hv;
  #pragma unroll
  for (int i = 0; i < 8; ++i) hv[i] = (short)f2bf(f[i]);
  *(short8v*)(Chi + (size_t)gid * 8) = hv;
}

// Main: 256x256 tile, 16 K-tiles of BK=32, 8 waves (2x4), per-wave 128x64.
// 4-deep ring, counted vmcnt(8), ONE barrier per K-tile, stage after MFMAs.
template<bool PRESPLIT>
__global__ __launch_bounds__(512, 2) void gemm_att_k(
    const float* __restrict__ ctx, const short* __restrict__ Chi,
    const short* __restrict__ Whi,
    const float* __restrict__ inp,
    const float* __restrict__ bc0, const float* __restrict__ bc1,
    const float* __restrict__ bc2, const float* __restrict__ bc3,
    const float* __restrict__ V, float* __restrict__ att) {
  __shared__ __align__(16) short smem[4][2][8192];   // 128 KiB: [ring][A|B]
  __shared__ float sV[256], sPre[256];

  const int t = threadIdx.x;
  int d = blockIdx.x + (blockIdx.y << 3);
  int work = (d & 7) * 256 + (d >> 3);           // XCD-contiguous chunks
  int mt = work >> 3, nt = work & 7;
  int b = mt >> 3;
  int g = nt >> 1, h0 = (nt & 1) * 256;

  if (t < 256) {
    const float* bc = (g == 0) ? bc0 : (g == 1) ? bc1 : (g == 2) ? bc2 : bc3;
    sV[t] = V[h0 + t];
    sPre[t] = inp[b * 512 + h0 + t] + bc[h0 + t];
  }

  const int toff = t * 8;   // t*16 bytes; tile region = 8192 shorts
  auto stageA = [&](int tile) {
    const short* gA = Chi + (((size_t)mt * 16 + tile) << 13) + toff;
    short* lA = &smem[tile & 3][0][0];
    gl_lds16(gA,        lA + toff);
    gl_lds16(gA + 4096, lA + toff + 4096);
  };
  auto stageB = [&](int tile) {
    const short* gB = Whi + (((size_t)nt * 16 + tile) << 13) + toff;
    short* lB = &smem[tile & 3][1][0];
    gl_lds16(gB,        lB + toff);
    gl_lds16(gB + 4096, lB + toff + 4096);
  };
  auto stageA_reg = [&](int tile) {    // fallback: fp32 ctx -> bf16 ds_write
    #pragma unroll
    for (int pass = 0; pass < 2; ++pass) {
      int cc = pass * 512 + t;
      int c = cc & 3, r = cc >> 2;
      int k = tile * 32 + c * 8;
      const float* src = ctx + ((size_t)mt * 256 + r) * 512 + k;
      float f[8];
      *(float4*)&f[0] = *(const float4*)src;
      *(float4*)&f[4] = *(const float4*)(src + 4);
      short8v hv;
      #pragma unroll
      for (int i = 0; i < 8; ++i) hv[i] = (short)f2bf(f[i]);
      *(short8v*)(&smem[tile & 3][0][r * 32 + c * 8]) = hv;
    }
  };

  f32x4 acc[8][4];
  #pragma unroll
  for (int i = 0; i < 8; ++i)
    #pragma unroll
    for (int j = 0; j < 4; ++j) acc[i][j] = (f32x4){0.f, 0.f, 0.f, 0.f};

  const int lane = t & 63, wid = t >> 6;
  const int wr = wid >> 2, wc = wid & 3;
  const int fr = lane & 15, fq = lane >> 4;
  const int abase = (wr * 128 + fr) * 32 + fq * 8;
  const int bbase = (wc * 64 + fr) * 32 + fq * 8;

  if constexpr (PRESPLIT) {
    stageA(0); stageB(0); stageA(1); stageB(1); stageA(2); stageB(2);
    WAITV8;
  } else {
    stageA_reg(0); stageB(0);
    WAITV0; WAITL;
  }
  BARR;

  #pragma unroll 4
  for (int tt = 0; tt < 16; ++tt) {
    const short* sa = &smem[tt & 3][0][0];
    const short* sb = &smem[tt & 3][1][0];
    bf16x8 a[8], b0, b1, b2, b3;
    #pragma unroll
    for (int mi = 0; mi < 8; ++mi)
      a[mi] = *(const bf16x8*)(sa + abase + mi * 512);
    b0 = *(const bf16x8*)(sb + bbase);
    b1 = *(const bf16x8*)(sb + bbase + 512);
    b2 = *(const bf16x8*)(sb + bbase + 1024);
    b3 = *(const bf16x8*)(sb + bbase + 1536);
    WAITL;
    __builtin_amdgcn_s_setprio(1);
    #pragma unroll
    for (int mi = 0; mi < 8; ++mi) {
      acc[mi][0] = __builtin_amdgcn_mfma_f32_16x16x32_bf16(a[mi], b0, acc[mi][0], 0, 0, 0);
      acc[mi][1] = __builtin_amdgcn_mfma_f32_16x16x32_bf16(a[mi], b1, acc[mi][1], 0, 0, 0);
    }
    #pragma unroll
    for (int mi = 0; mi < 8; ++mi) {
      acc[mi][2] = __builtin_amdgcn_mfma_f32_16x16x32_bf16(a[mi], b2, acc[mi][2], 0, 0, 0);
      acc[mi][3] = __builtin_amdgcn_mfma_f32_16x16x32_bf16(a[mi], b3, acc[mi][3], 0, 0, 0);
    }
    __builtin_amdgcn_s_setprio(0);
    __builtin_amdgcn_sched_barrier(0);
    if constexpr (PRESPLIT) {
      if (tt <= 12) { stageA(tt + 3); stageB(tt + 3); }
      if (tt <= 12)      { WAITV8; }
      else if (tt == 13) { WAITV4; }
      else if (tt == 14) { WAITV0; }
    } else {
      if (tt < 15) { stageA_reg(tt + 1); stageB(tt + 1); WAITV0; WAITL; }
    }
    BARR;
  }

  // epilogue: att[b, g*2048 + s] += sum_n V[h]*tanh(pre[h] + Y[n,s])
  float vV[4], vP[4];
  #pragma unroll
  for (int ni = 0; ni < 4; ++ni) {
    int j = wc * 64 + ni * 16 + fr;
    vV[ni] = sV[j];
    vP[ni] = sPre[j];
  }
  size_t abatt = (size_t)b * 8192 + (size_t)g * 2048;
  #pragma unroll
  for (int mi = 0; mi < 8; ++mi) {
    #pragma unroll
    for (int r = 0; r < 4; ++r) {
      float sum = 0.f;
      #pragma unroll
      for (int ni = 0; ni < 4; ++ni)
        sum += vV[ni] * tanh_fast(vP[ni] + acc[mi][ni][r]);
      sum = dpp_row_reduce(sum);
      if (fr == 15) {                  // row sum lands in lane 15 (row_shr)
        int s = (mt * 256 + wr * 128 + mi * 16 + fq * 4 + r) & 2047;
        atomicAdd(&att[abatt + s], sum);
      }
    }
  }
}

// Fused tail: max + denom + candidates, exact fp32 rescore, final outputs.
__global__ __launch_bounds__(256) void tail_k(const float* __restrict__ att,
    const unsigned char* __restrict__ mask, const float* __restrict__ ctx,
    const float* __restrict__ Wc0, const float* __restrict__ Wc1,
    const float* __restrict__ Wc2, const float* __restrict__ Wc3,
    const float* __restrict__ bc0, const float* __restrict__ bc1,
    const float* __restrict__ bc2, const float* __restrict__ bc3,
    const float* __restrict__ inp, const float* __restrict__ V,
    float* __restrict__ out) {
  int b = blockIdx.x, t = threadIdx.x;
  __shared__ float sred[256];
  __shared__ float sctx[512];
  __shared__ int scnt;
  __shared__ int scand_j[NCAND];
  __shared__ float scand_a[NCAND];
  __shared__ float sexact[NCAND];

  if (t == 0) scnt = 0;
  float bm = -1e30f;
  for (int j = t; j < 8192; j += 256) {
    if (mask[b * 2048 + (j & 2047)]) continue;
    bm = fmaxf(bm, att[(size_t)b * 8192 + j]);
  }
  sred[t] = bm;
  __syncthreads();
  for (int s2 = 128; s2 > 0; s2 >>= 1) {
    if (t < s2) sred[t] = fmaxf(sred[t], sred[t + s2]);
    __syncthreads();
  }
  float mx = sred[0];
  float Lref = 10.f * tanhf(mx);
  __syncthreads();
  float se = 0.f;
  for (int j = t; j < 8192; j += 256) {
    if (mask[b * 2048 + (j & 2047)]) continue;
    float a = att[(size_t)b * 8192 + j];
    se += expf(10.f * tanhf(a) - Lref);
    if (a >= mx - MARGIN) {
      int slot = atomicAdd(&scnt, 1);
      if (slot < NCAND) { scand_j[slot] = j; scand_a[slot] = a; }
    }
  }
  sred[t] = se;
  __syncthreads();
  for (int s2 = 128; s2 > 0; s2 >>= 1) {
    if (t < s2) sred[t] += sred[t + s2];
    __syncthreads();
  }
  float den = sred[0];
  int n = min(scnt, NCAND);
  for (int j = t; j < 2048; j += 256)
    out[64 + b * 2048 + j] = mask[b * 2048 + j] ? 1.0f : 0.0f;
  for (int i = 0; i < n; ++i) {
    int jj = scand_j[i];
    int g = jj >> 11, s = jj & 2047;
    const float* W  = (g == 0) ? Wc0 : (g == 1) ? Wc1 : (g == 2) ? Wc2 : Wc3;
    const float* bc = (g == 0) ? bc0 : (g == 1) ? bc1 : (g == 2) ? bc2 : bc3;
    const float* cr = ctx + ((size_t)b * 2048 + s) * 512;
    __syncthreads();
    sctx[t] = cr[t];
    sctx[t + 256] = cr[t + 256];
    __syncthreads();
    float total = 0.f;
    #pragma unroll
    for (int hh = 0; hh < 2; ++hh) {
      int h = t + hh * 256;
      const float* wrp = W + (size_t)h * 512;
      float acc = 0.f;
      #pragma unroll 4
      for (int k = 0; k < 512; k += 4) {
        float4 wv = *(const float4*)(wrp + k);
        acc += wv.x * sctx[k] + wv.y * sctx[k + 1] + wv.z * sctx[k + 2] + wv.w * sctx[k + 3];
      }
      total += V[h] * tanhf(inp[b * 512 + h] + bc[h] + acc);
    }
    sred[t] = total;
    __syncthreads();
    for (int s2 = 128; s2 > 0; s2 >>= 1) {
      if (t < s2) sred[t] += sred[t + s2];
      __syncthreads();
    }
    if (t == 0) sexact[i] = sred[0];
  }
  __syncthreads();
  if (t == 0) {
    float dd = den, best = -1e30f;
    int bj = 0x7fffffff;
    for (int i = 0; i < n; ++i) {
      float e = sexact[i];
      int j = scand_j[i];
      dd += expf(10.f * tanhf(e) - Lref) - expf(10.f * tanhf(scand_a[i]) - Lref);
      if (e > best || (e == best && j < bj)) { best = e; bj = j; }
    }
    out[b] = (float)bj;
    out[32 + b] = expf(10.f * tanhf(best) - Lref) / dd;
  }
}

extern "C" void kernel_launch(void* const* d_in, const int* in_sizes, int n_in,
                              void* d_out, int out_size, void* d_ws, size_t ws_size,
                              hipStream_t stream) {
  const float* x    = (const float*)d_in[0];
  const float* ctx  = (const float*)d_in[1];
  const unsigned char* mask = (const unsigned char*)d_in[2];
  const float* Wi   = (const float*)d_in[3];
  const float* bi   = (const float*)d_in[4];
  const float* Wc0  = (const float*)d_in[5];
  const float* bc0  = (const float*)d_in[6];
  const float* Wc1  = (const float*)d_in[7];
  const float* bc1  = (const float*)d_in[8];
  const float* Wc2  = (const float*)d_in[9];
  const float* bc2  = (const float*)d_in[10];
  const float* Wc3  = (const float*)d_in[11];
  const float* bc3  = (const float*)d_in[12];
  const float* V    = (const float*)d_in[13];
  float* out = (float*)d_out;

  float* inp    = (float*)d_ws;            // 16384 f32
  float* att    = inp + 16384;             // 262144 f32
  short* Whi    = (short*)(att + 262144);  // 1048576 shorts
  short* Chi    = Whi + 1048576;           // 33554432 shorts
  size_t need = (size_t)((char*)(Chi + 33554432) - (char*)d_ws);
  bool presplit = ws_size >= need;

  hipMemsetAsync(att, 0, 262144 * sizeof(float), stream);
  prep_inp_k<<<64, 256, 0, stream>>>(x, Wi, bi, inp);
  prep_w_pack_k<<<512, 256, 0, stream>>>(Wc0, Wc1, Wc2, Wc3, Whi);
  if (presplit) {
    prep_ctx_pack_k<<<16384, 256, 0, stream>>>(ctx, Chi);
    gemm_att_k<true><<<dim3(8, 256), 512, 0, stream>>>(ctx, Chi, Whi,
        inp, bc0, bc1, bc2, bc3, V, att);
  } else {
    gemm_att_k<false><<<dim3(8, 256), 512, 0, stream>>>(ctx, nullptr, Whi,
        inp, bc0, bc1, bc2, bc3, V, att);
  }
  tail_k<<<32, 256, 0, stream>>>(att, mask, ctx, Wc0, Wc1, Wc2, Wc3,
      bc0, bc1, bc2, bc3, inp, V, out);
}